// Round 1
// baseline (432.050 us; speedup 1.0000x reference)
//
#include <hip/hip_runtime.h>

// Problem constants (fixed by reference)
#define EMBED 1024
#define NHEAD 16
#define HDIM  64
#define BATCH 2
#define SEQ   2048
#define MTOK  (BATCH * SEQ)   // 4096 tokens

typedef __bf16 bf16x8 __attribute__((ext_vector_type(8)));
typedef float  f32x4  __attribute__((ext_vector_type(4)));

__device__ __forceinline__ unsigned short f2bf(float f) {
  unsigned int u = __float_as_uint(f);
  u += 0x7fffu + ((u >> 16) & 1u);   // round-to-nearest-even
  return (unsigned short)(u >> 16);
}

// ---------------- cast / transpose-cast ----------------
__global__ void cast_bf16_k(const float* __restrict__ src,
                            unsigned short* __restrict__ dst, int n) {
  for (int i = blockIdx.x * blockDim.x + threadIdx.x; i < n;
       i += gridDim.x * blockDim.x)
    dst[i] = f2bf(src[i]);
}

// dst[n][k] = src[k][n], 1024x1024
__global__ void transpose_cast_k(const float* __restrict__ src,
                                 unsigned short* __restrict__ dst) {
  for (int i = blockIdx.x * blockDim.x + threadIdx.x; i < EMBED * EMBED;
       i += gridDim.x * blockDim.x) {
    int n = i >> 10, k = i & 1023;
    dst[i] = f2bf(src[(k << 10) + n]);
  }
}

// ---------------- GEMM: C[M=4096][N=1024] = A[M][1024] * Bt[N][1024]^T ----------------
// mode 0: bf16 out, [B][H][S][Dh] (Q with scale=0.125, K with scale=1)
// mode 2: bf16 out, [B][H][Dh][S] (V transposed)
// mode 3: fp32 out, [M][N] (final output)
__global__ __launch_bounds__(256, 2)
void gemm_bt_k(const unsigned short* __restrict__ A,
               const unsigned short* __restrict__ Bt,
               const float* __restrict__ bias,
               void* __restrict__ out, float scale, int mode) {
  __shared__ unsigned short As[128][72];   // k-stride 72: 144B rows, 16B aligned, 2-way banks
  __shared__ unsigned short Bs[128][72];
  const int tid  = threadIdx.x;
  const int lane = tid & 63;
  const int wave = tid >> 6;
  const int wm = (wave >> 1) * 64, wn = (wave & 1) * 64;   // 2x2 waves, 64x64 each
  const int row0 = blockIdx.x * 128, col0 = blockIdx.y * 128;
  const int lr = lane & 15, quad = lane >> 4, q8 = quad * 8;
  const int rs = tid >> 3;            // staging row base (0..31)
  const int kc = (tid & 7) * 8;       // staging k chunk

  const f32x4 fzero = {0.f, 0.f, 0.f, 0.f};
  f32x4 acc[4][4];
#pragma unroll
  for (int i = 0; i < 4; ++i)
#pragma unroll
    for (int j = 0; j < 4; ++j) acc[i][j] = fzero;

  for (int k0 = 0; k0 < EMBED; k0 += 64) {
#pragma unroll
    for (int s = 0; s < 4; ++s) {
      int r = rs + 32 * s;
      *reinterpret_cast<bf16x8*>(&As[r][kc]) =
          *reinterpret_cast<const bf16x8*>(&A[(size_t)(row0 + r) * EMBED + k0 + kc]);
      *reinterpret_cast<bf16x8*>(&Bs[r][kc]) =
          *reinterpret_cast<const bf16x8*>(&Bt[(size_t)(col0 + r) * EMBED + k0 + kc]);
    }
    __syncthreads();
#pragma unroll
    for (int kk = 0; kk < 64; kk += 32) {
      bf16x8 af[4], bv[4];
#pragma unroll
      for (int i = 0; i < 4; ++i)
        af[i] = *reinterpret_cast<const bf16x8*>(&As[wm + i * 16 + lr][kk + q8]);
#pragma unroll
      for (int j = 0; j < 4; ++j)
        bv[j] = *reinterpret_cast<const bf16x8*>(&Bs[wn + j * 16 + lr][kk + q8]);
#pragma unroll
      for (int i = 0; i < 4; ++i)
#pragma unroll
        for (int j = 0; j < 4; ++j)
          acc[i][j] = __builtin_amdgcn_mfma_f32_16x16x32_bf16(af[i], bv[j],
                                                              acc[i][j], 0, 0, 0);
    }
    __syncthreads();
  }

  // epilogue: D[row=quad*4+r][col=lane&15] per 16x16 tile (m89-verified)
#pragma unroll
  for (int i = 0; i < 4; ++i) {
#pragma unroll
    for (int j = 0; j < 4; ++j) {
      const int col = col0 + wn + j * 16 + lr;
      const float bvv = bias[col];
#pragma unroll
      for (int r = 0; r < 4; ++r) {
        const int row = row0 + wm + i * 16 + quad * 4 + r;
        const float v = (acc[i][j][r] + bvv) * scale;
        const int b = row >> 11, s = row & (SEQ - 1);
        const int h = col >> 6, d = col & (HDIM - 1);
        if (mode == 0) {
          ((unsigned short*)out)[((((size_t)b * NHEAD + h) * SEQ + s) << 6) + d] = f2bf(v);
        } else if (mode == 2) {
          ((unsigned short*)out)[(((size_t)b * NHEAD + h) * HDIM + d) * SEQ + s] = f2bf(v);
        } else {
          ((float*)out)[((size_t)row << 10) + col] = v;
        }
      }
    }
  }
}

// ---------------- flash attention ----------------
// grid (32 q-tiles, 32 bh); 4 waves, each owns 16 q rows; K/V tiles of 64 keys.
__global__ __launch_bounds__(256, 2)
void attn_k(const unsigned short* __restrict__ Qb,   // [B][H][S][Dh], pre-scaled
            const unsigned short* __restrict__ Kb,   // [B][H][S][Dh]
            const unsigned short* __restrict__ Vt,   // [B][H][Dh][S]
            unsigned short* __restrict__ Ctx) {      // [B][S][EMBED] bf16
  __shared__ unsigned short Qs[64][72];
  __shared__ unsigned short Ks[64][72];
  __shared__ unsigned short Vs[64][72];
  __shared__ unsigned short Ps[64][72];
  const int tid = threadIdx.x, lane = tid & 63, wave = tid >> 6;
  const int lr = lane & 15, quad = lane >> 4, q8 = quad * 8;
  const int qt = blockIdx.x, bh = blockIdx.y;
  const size_t base = (size_t)bh * SEQ * HDIM;
  const int rs = tid >> 3, kc = (tid & 7) * 8;

#pragma unroll
  for (int s = 0; s < 2; ++s) {
    int r = rs + 32 * s;
    *reinterpret_cast<bf16x8*>(&Qs[r][kc]) =
        *reinterpret_cast<const bf16x8*>(&Qb[base + (size_t)(qt * 64 + r) * HDIM + kc]);
  }

  float m_run[4] = {-1e30f, -1e30f, -1e30f, -1e30f};
  float l_run[4] = {0.f, 0.f, 0.f, 0.f};
  const f32x4 fzero = {0.f, 0.f, 0.f, 0.f};
  f32x4 oacc[4];
#pragma unroll
  for (int d = 0; d < 4; ++d) oacc[d] = fzero;

  for (int kt = 0; kt < SEQ / 64; ++kt) {
#pragma unroll
    for (int s = 0; s < 2; ++s) {
      int r = rs + 32 * s;
      *reinterpret_cast<bf16x8*>(&Ks[r][kc]) =
          *reinterpret_cast<const bf16x8*>(&Kb[base + (size_t)(kt * 64 + r) * HDIM + kc]);
      *reinterpret_cast<bf16x8*>(&Vs[r][kc]) =
          *reinterpret_cast<const bf16x8*>(&Vt[base + (size_t)r * SEQ + kt * 64 + kc]);
    }
    __syncthreads();

    // S[16q][64keys]: A = Q rows, B = K^T (Ks natural layout is Bt)
    f32x4 sc[4];
#pragma unroll
    for (int nt = 0; nt < 4; ++nt) {
      f32x4 a = fzero;
#pragma unroll
      for (int kk = 0; kk < 64; kk += 32) {
        bf16x8 qa = *reinterpret_cast<const bf16x8*>(&Qs[wave * 16 + lr][kk + q8]);
        bf16x8 kb = *reinterpret_cast<const bf16x8*>(&Ks[nt * 16 + lr][kk + q8]);
        a = __builtin_amdgcn_mfma_f32_16x16x32_bf16(qa, kb, a, 0, 0, 0);
      }
      sc[nt] = a;
    }

    // online softmax: row r of this wave's quad = q row quad*4+r
    float mx[4], al[4];
#pragma unroll
    for (int r = 0; r < 4; ++r) {
      float m = fmaxf(fmaxf(sc[0][r], sc[1][r]), fmaxf(sc[2][r], sc[3][r]));
#pragma unroll
      for (int off = 1; off < 16; off <<= 1)
        m = fmaxf(m, __shfl_xor(m, off));
      float mnew = fmaxf(m_run[r], m);
      al[r] = __expf(m_run[r] - mnew);
      m_run[r] = mnew;
      mx[r] = mnew;
    }
    float p[4][4];
#pragma unroll
    for (int nt = 0; nt < 4; ++nt)
#pragma unroll
      for (int r = 0; r < 4; ++r)
        p[nt][r] = __expf(sc[nt][r] - mx[r]);
#pragma unroll
    for (int r = 0; r < 4; ++r) {
      float s = (p[0][r] + p[1][r]) + (p[2][r] + p[3][r]);
#pragma unroll
      for (int off = 1; off < 16; off <<= 1)
        s += __shfl_xor(s, off);
      l_run[r] = l_run[r] * al[r] + s;
    }
#pragma unroll
    for (int d = 0; d < 4; ++d)
#pragma unroll
      for (int r = 0; r < 4; ++r)
        oacc[d][r] *= al[r];

    // P: C-layout -> LDS -> A-layout (per-wave region, m120 pattern)
#pragma unroll
    for (int nt = 0; nt < 4; ++nt)
#pragma unroll
      for (int r = 0; r < 4; ++r)
        Ps[wave * 16 + quad * 4 + r][nt * 16 + lr] = f2bf(p[nt][r]);
    __threadfence_block();   // order Ps writes before reads (same wave)

#pragma unroll
    for (int d = 0; d < 4; ++d) {
#pragma unroll
      for (int kk = 0; kk < 64; kk += 32) {
        bf16x8 pa = *reinterpret_cast<const bf16x8*>(&Ps[wave * 16 + lr][kk + q8]);
        bf16x8 vb = *reinterpret_cast<const bf16x8*>(&Vs[d * 16 + lr][kk + q8]);
        oacc[d] = __builtin_amdgcn_mfma_f32_16x16x32_bf16(pa, vb, oacc[d], 0, 0, 0);
      }
    }
    __syncthreads();
  }

  const int b = bh >> 4, h = bh & 15;
#pragma unroll
  for (int d = 0; d < 4; ++d)
#pragma unroll
    for (int r = 0; r < 4; ++r) {
      const int q = qt * 64 + wave * 16 + quad * 4 + r;
      const float v = oacc[d][r] / l_run[r];
      Ctx[(((size_t)b * SEQ + q) << 10) + h * 64 + d * 16 + lr] = f2bf(v);
    }
}

// ---------------- launch ----------------
extern "C" void kernel_launch(void* const* d_in, const int* in_sizes, int n_in,
                              void* d_out, int out_size, void* d_ws, size_t ws_size,
                              hipStream_t stream) {
  const float* X  = (const float*)d_in[0];
  const float* Wq = (const float*)d_in[1];
  const float* bq = (const float*)d_in[2];
  const float* Wk = (const float*)d_in[3];
  const float* bk = (const float*)d_in[4];
  const float* Wv = (const float*)d_in[5];
  const float* bv = (const float*)d_in[6];
  const float* Wo = (const float*)d_in[7];
  const float* bo = (const float*)d_in[8];

  unsigned short* ws = (unsigned short*)d_ws;
  unsigned short* Xbf = ws;                               // 4M
  unsigned short* WqT = Xbf + (size_t)MTOK * EMBED;       // 1M
  unsigned short* WkT = WqT + (size_t)EMBED * EMBED;
  unsigned short* WvT = WkT + (size_t)EMBED * EMBED;
  unsigned short* WoT = WvT + (size_t)EMBED * EMBED;
  unsigned short* Qb  = WoT + (size_t)EMBED * EMBED;      // 4M
  unsigned short* Kb  = Qb + (size_t)MTOK * EMBED;
  unsigned short* Vt  = Kb + (size_t)MTOK * EMBED;
  unsigned short* Ctx = Vt + (size_t)MTOK * EMBED;        // 4M  (total 48 MB)

  cast_bf16_k<<<4096, 256, 0, stream>>>(X, Xbf, MTOK * EMBED);
  transpose_cast_k<<<2048, 256, 0, stream>>>(Wq, WqT);
  transpose_cast_k<<<2048, 256, 0, stream>>>(Wk, WkT);
  transpose_cast_k<<<2048, 256, 0, stream>>>(Wv, WvT);
  transpose_cast_k<<<2048, 256, 0, stream>>>(Wo, WoT);

  dim3 gg(MTOK / 128, EMBED / 128);
  gemm_bt_k<<<gg, 256, 0, stream>>>(Xbf, WqT, bq, Qb, 0.125f, 0);  // Q, pre-scaled 1/sqrt(64)
  gemm_bt_k<<<gg, 256, 0, stream>>>(Xbf, WkT, bk, Kb, 1.0f, 0);    // K
  gemm_bt_k<<<gg, 256, 0, stream>>>(Xbf, WvT, bv, Vt, 1.0f, 2);    // V transposed

  attn_k<<<dim3(SEQ / 64, BATCH * NHEAD), 256, 0, stream>>>(Qb, Kb, Vt, Ctx);

  gemm_bt_k<<<gg, 256, 0, stream>>>(Ctx, WoT, bo, d_out, 1.0f, 3); // output proj
}

// Round 2
// 210.704 us; speedup vs baseline: 2.0505x; 2.0505x over previous
//
#include <hip/hip_runtime.h>

#define EMBED 1024
#define NHEAD 16
#define HDIM  64
#define BATCH 2
#define SEQ   2048
#define MTOK  (BATCH * SEQ)   // 4096 tokens

typedef __bf16 bf16x8 __attribute__((ext_vector_type(8)));
typedef __bf16 bf16x4 __attribute__((ext_vector_type(4)));
typedef float  f32x4  __attribute__((ext_vector_type(4)));

__device__ __forceinline__ unsigned short f2bf(float f) {
  unsigned int u = __float_as_uint(f);
  u += 0x7fffu + ((u >> 16) & 1u);   // RNE
  return (unsigned short)(u >> 16);
}
__device__ __forceinline__ __bf16 f2bf16(float f) {
  unsigned short s = f2bf(f);
  return *reinterpret_cast<__bf16*>(&s);
}

// async global->LDS, 16B per lane; LDS dest = wave-uniform base + lane*16
__device__ __forceinline__ void gload_lds16(const unsigned short* g, unsigned short* l) {
  __builtin_amdgcn_global_load_lds((__attribute__((address_space(1))) void*)g,
                                   (__attribute__((address_space(3))) void*)l, 16, 0, 0);
}

// ---------------- cast X -> bf16 (vectorized) ----------------
__global__ void cast_bf16_k(const float* __restrict__ src,
                            unsigned short* __restrict__ dst, int n4) {
  int i = blockIdx.x * blockDim.x + threadIdx.x;
  if (i < n4) {
    float4 f = reinterpret_cast<const float4*>(src)[i];
    ushort4 u;
    u.x = f2bf(f.x); u.y = f2bf(f.y); u.z = f2bf(f.z); u.w = f2bf(f.w);
    reinterpret_cast<ushort4*>(dst)[i] = u;
  }
}

// ---------------- 4 fused LDS-tiled transpose-casts: dst[n][k] = bf16(src[k][n]) ----------------
__global__ __launch_bounds__(256)
void transpose_cast4_k(const float* __restrict__ s0, const float* __restrict__ s1,
                       const float* __restrict__ s2, const float* __restrict__ s3,
                       unsigned short* __restrict__ d0, unsigned short* __restrict__ d1,
                       unsigned short* __restrict__ d2, unsigned short* __restrict__ d3) {
  const float* s; unsigned short* d;
  switch (blockIdx.z) {
    case 0: s = s0; d = d0; break;
    case 1: s = s1; d = d1; break;
    case 2: s = s2; d = d2; break;
    default: s = s3; d = d3; break;
  }
  __shared__ unsigned short T[64][65];
  const int k0 = blockIdx.x * 64, n0 = blockIdx.y * 64;
  for (int i = threadIdx.x; i < 4096; i += 256) {
    int r = i >> 6, c = i & 63;             // read coalesced over n
    T[c][r] = f2bf(s[(size_t)(k0 + r) * EMBED + n0 + c]);
  }
  __syncthreads();
  for (int i = threadIdx.x; i < 4096; i += 256) {
    int r = i >> 6, c = i & 63;             // write coalesced over k
    d[(size_t)(n0 + r) * EMBED + k0 + c] = T[r][c];
  }
}

// ---------------- GEMM  C[M][N] = A[M][1024] * Bt[N][1024]^T ----------------
// MODE 0: fused QKV epilogue (N=3072): col<1024 -> Q (scaled 0.125, [B][H][S][Dh]),
//         col<2048 -> K ([B][H][S][Dh]), else -> V transposed ([B][H][Dh][S])
// MODE 1: fp32 out [M][1024] + bias
template<int MODE, int BM>
__global__ __launch_bounds__(256, 2)
void gemm_k(const unsigned short* __restrict__ A,
            const unsigned short* __restrict__ Bt,
            const float* __restrict__ b0, const float* __restrict__ b1,
            const float* __restrict__ b2,
            unsigned short* __restrict__ oQ, unsigned short* __restrict__ oK,
            unsigned short* __restrict__ oV, float* __restrict__ oF) {
  constexpr int MI = BM / 32;               // row-frags per wave
  __shared__ unsigned short As[BM][64];     // unpadded, XOR-swizzled chunks
  __shared__ unsigned short Bs[128][64];
  const int tid = threadIdx.x, lane = tid & 63, wave = tid >> 6;
  const int lr = lane & 15, quad = lane >> 4;
  const int wm = (wave >> 1) * (BM / 2), wn = (wave & 1) * 64;
  const int row0 = blockIdx.x * BM, col0 = blockIdx.y * 128;
  const int srow = lane >> 3, sc = lane & 7;
  const int sw0 = (quad ^ (lr & 7)) * 8;            // phys chunk for kk=0
  const int sw1 = ((quad ^ 4) ^ (lr & 7)) * 8;      // phys chunk for kk=32

  const f32x4 fz = {0.f, 0.f, 0.f, 0.f};
  f32x4 acc[MI][4];
#pragma unroll
  for (int i = 0; i < MI; ++i)
#pragma unroll
    for (int j = 0; j < 4; ++j) acc[i][j] = fz;

  for (int k0 = 0; k0 < EMBED; k0 += 64) {
#pragma unroll
    for (int g = 0; g < BM / 32; ++g) {     // stage A: swizzled chunk per lane
      int rbase = wave * (BM / 4) + g * 8;
      int row = rbase + srow;
      gload_lds16(&A[(size_t)(row0 + row) * EMBED + k0 + ((sc ^ (row & 7)) * 8)],
                  &As[rbase][0]);
    }
#pragma unroll
    for (int g = 0; g < 4; ++g) {           // stage B
      int rbase = wave * 32 + g * 8;
      int row = rbase + srow;
      gload_lds16(&Bt[(size_t)(col0 + row) * EMBED + k0 + ((sc ^ (row & 7)) * 8)],
                  &Bs[rbase][0]);
    }
    __syncthreads();
#pragma unroll
    for (int kk = 0; kk < 64; kk += 32) {
      const int so = (kk == 0) ? sw0 : sw1;
      bf16x8 af[MI], bv[4];
#pragma unroll
      for (int i = 0; i < MI; ++i)
        af[i] = *reinterpret_cast<const bf16x8*>(&As[wm + i * 16 + lr][so]);
#pragma unroll
      for (int j = 0; j < 4; ++j)
        bv[j] = *reinterpret_cast<const bf16x8*>(&Bs[wn + j * 16 + lr][so]);
#pragma unroll
      for (int i = 0; i < MI; ++i)
#pragma unroll
        for (int j = 0; j < 4; ++j)
          acc[i][j] = __builtin_amdgcn_mfma_f32_16x16x32_bf16(af[i], bv[j],
                                                              acc[i][j], 0, 0, 0);
    }
    __syncthreads();
  }

#pragma unroll
  for (int i = 0; i < MI; ++i) {
#pragma unroll
    for (int j = 0; j < 4; ++j) {
      const int col = col0 + wn + j * 16 + lr;
      if (MODE == 1) {
        const float bb = b0[col];
#pragma unroll
        for (int r = 0; r < 4; ++r) {
          const int row = row0 + wm + i * 16 + quad * 4 + r;
          oF[((size_t)row << 10) + col] = acc[i][j][r] + bb;
        }
      } else {
        const int which = col >> 10, cn = col & 1023;
        const float bb = (which == 0 ? b0 : which == 1 ? b1 : b2)[cn];
        const int h = cn >> 6, dd = cn & 63;
#pragma unroll
        for (int r = 0; r < 4; ++r) {
          const int row = row0 + wm + i * 16 + quad * 4 + r;
          const int b = row >> 11, ss = row & (SEQ - 1);
          float v = acc[i][j][r] + bb;
          if (which == 0) {
            oQ[((((size_t)b * NHEAD + h) * SEQ + ss) << 6) + dd] = f2bf(v * 0.125f);
          } else if (which == 1) {
            oK[((((size_t)b * NHEAD + h) * SEQ + ss) << 6) + dd] = f2bf(v);
          } else {
            oV[(((size_t)b * NHEAD + h) * HDIM + dd) * SEQ + ss] = f2bf(v);
          }
        }
      }
    }
  }
}

// ---------------- flash attention (S^T formulation) ----------------
// grid (32 q-tiles, 32 bh); 4 waves x 16 q rows; 64-key tiles.
// QK^T computed transposed (A=K, B=Q) so each lane's softmax state is scalar
// (q = lane&15): in-thread reduce + 2 shuffles. P^T emerges packed for b64
// writes; PV uses A=P (LDS round-trip), B=V^T rows.
__global__ __launch_bounds__(256, 4)
void attn_k(const unsigned short* __restrict__ Qb,   // [B][H][S][Dh], pre-scaled
            const unsigned short* __restrict__ Kb,   // [B][H][S][Dh]
            const unsigned short* __restrict__ Vt,   // [B][H][Dh][S]
            unsigned short* __restrict__ Ctx) {      // [B][S][EMBED] bf16
  __shared__ unsigned short Qs[64][64];   // all XOR-swizzled
  __shared__ unsigned short Ks[64][64];
  __shared__ unsigned short Vs[64][64];
  __shared__ unsigned short Ps[64][64];
  const int tid = threadIdx.x, lane = tid & 63, wave = tid >> 6;
  const int lr = lane & 15, quad = lane >> 4;
  const int qt = blockIdx.x, bh = blockIdx.y;
  const size_t base = (size_t)bh * SEQ * HDIM;
  const int srow = lane >> 3, sc = lane & 7;
  const int sw0 = (quad ^ (lr & 7)) * 8;
  const int sw1 = ((quad ^ 4) ^ (lr & 7)) * 8;

  // stage Q once
#pragma unroll
  for (int g = 0; g < 2; ++g) {
    int rbase = wave * 16 + g * 8;
    int row = rbase + srow;
    gload_lds16(&Qb[base + (size_t)(qt * 64 + row) * HDIM + ((sc ^ (row & 7)) * 8)],
                &Qs[rbase][0]);
  }
  // stage K/V tile 0
#pragma unroll
  for (int g = 0; g < 2; ++g) {
    int rbase = wave * 16 + g * 8;
    int row = rbase + srow;
    gload_lds16(&Kb[base + (size_t)row * HDIM + ((sc ^ (row & 7)) * 8)], &Ks[rbase][0]);
    gload_lds16(&Vt[base + (size_t)row * SEQ + ((sc ^ (row & 7)) * 8)], &Vs[rbase][0]);
  }
  __syncthreads();

  // hoist Q frags (B operand: n = q = lane&15)
  const bf16x8 qf0 = *reinterpret_cast<const bf16x8*>(&Qs[wave * 16 + lr][sw0]);
  const bf16x8 qf1 = *reinterpret_cast<const bf16x8*>(&Qs[wave * 16 + lr][sw1]);

  float m_run = -1e30f, l_run = 0.f;
  const f32x4 fz = {0.f, 0.f, 0.f, 0.f};
  f32x4 oacc[4];
#pragma unroll
  for (int d = 0; d < 4; ++d) oacc[d] = fz;

  for (int kt = 0;;) {
    // S^T[key][q]: A = K rows (m=key), B = Q (n=q)
    f32x4 sc4[4];
#pragma unroll
    for (int nt = 0; nt < 4; ++nt) {
      bf16x8 kf0 = *reinterpret_cast<const bf16x8*>(&Ks[nt * 16 + lr][sw0]);
      bf16x8 kf1 = *reinterpret_cast<const bf16x8*>(&Ks[nt * 16 + lr][sw1]);
      f32x4 a = __builtin_amdgcn_mfma_f32_16x16x32_bf16(kf0, qf0, fz, 0, 0, 0);
      sc4[nt] = __builtin_amdgcn_mfma_f32_16x16x32_bf16(kf1, qf1, a, 0, 0, 0);
    }

    // softmax for q = lane&15: in-thread reduce over 16 keys, 2 shuffles over quads
    float mloc = -1e30f;
#pragma unroll
    for (int nt = 0; nt < 4; ++nt)
#pragma unroll
      for (int r = 0; r < 4; ++r) mloc = fmaxf(mloc, sc4[nt][r]);
    mloc = fmaxf(mloc, __shfl_xor(mloc, 16));
    mloc = fmaxf(mloc, __shfl_xor(mloc, 32));
    const float mnew = fmaxf(m_run, mloc);
    const float alpha = __expf(m_run - mnew);
    m_run = mnew;

    float psum = 0.f;
#pragma unroll
    for (int nt = 0; nt < 4; ++nt) {
      bf16x4 pk;
#pragma unroll
      for (int r = 0; r < 4; ++r) {
        float p = __expf(sc4[nt][r] - mnew);
        psum += p;
        pk[r] = f2bf16(p);
      }
      // P^T write: row q=lr (this wave's region), keys nt*16+quad*4+[0,4)
      const int lc = nt * 2 + (quad >> 1);               // logical 8-short chunk
      const int pc = lc ^ (lr & 7);                      // swizzled
      *reinterpret_cast<bf16x4*>(&Ps[wave * 16 + lr][pc * 8 + (quad & 1) * 4]) = pk;
    }
    psum += __shfl_xor(psum, 16);
    psum += __shfl_xor(psum, 32);
    l_run = l_run * alpha + psum;

    // rescale O (rows q = quad*4+r need alpha(q) -> broadcast from lane q)
    float alr[4];
#pragma unroll
    for (int r = 0; r < 4; ++r) alr[r] = __shfl(alpha, quad * 4 + r);
#pragma unroll
    for (int d = 0; d < 4; ++d)
#pragma unroll
      for (int r = 0; r < 4; ++r) oacc[d][r] *= alr[r];

    __threadfence_block();   // Ps writes -> reads (same wave region)

    // O += P * V : A = P (m=q), B = V^T rows (n=d)
    const bf16x8 pa0 = *reinterpret_cast<const bf16x8*>(&Ps[wave * 16 + lr][sw0]);
    const bf16x8 pa1 = *reinterpret_cast<const bf16x8*>(&Ps[wave * 16 + lr][sw1]);
#pragma unroll
    for (int d = 0; d < 4; ++d) {
      bf16x8 vb0 = *reinterpret_cast<const bf16x8*>(&Vs[d * 16 + lr][sw0]);
      bf16x8 vb1 = *reinterpret_cast<const bf16x8*>(&Vs[d * 16 + lr][sw1]);
      oacc[d] = __builtin_amdgcn_mfma_f32_16x16x32_bf16(pa0, vb0, oacc[d], 0, 0, 0);
      oacc[d] = __builtin_amdgcn_mfma_f32_16x16x32_bf16(pa1, vb1, oacc[d], 0, 0, 0);
    }

    if (++kt == SEQ / 64) break;
    __syncthreads();         // everyone done reading Ks/Vs
#pragma unroll
    for (int g = 0; g < 2; ++g) {
      int rbase = wave * 16 + g * 8;
      int row = rbase + srow;
      gload_lds16(&Kb[base + (size_t)(kt * 64 + row) * HDIM + ((sc ^ (row & 7)) * 8)],
                  &Ks[rbase][0]);
      gload_lds16(&Vt[base + (size_t)row * SEQ + kt * 64 + ((sc ^ (row & 7)) * 8)],
                  &Vs[rbase][0]);
    }
    __syncthreads();         // staged data visible
  }

  const int b = bh >> 4, h = bh & 15;
  float linv[4];
#pragma unroll
  for (int r = 0; r < 4; ++r) linv[r] = 1.0f / __shfl(l_run, quad * 4 + r);
#pragma unroll
  for (int d = 0; d < 4; ++d)
#pragma unroll
    for (int r = 0; r < 4; ++r) {
      const int q = qt * 64 + wave * 16 + quad * 4 + r;
      Ctx[(((size_t)b * SEQ + q) << 10) + h * 64 + d * 16 + lr] =
          f2bf(oacc[d][r] * linv[r]);
    }
}

// ---------------- launch ----------------
extern "C" void kernel_launch(void* const* d_in, const int* in_sizes, int n_in,
                              void* d_out, int out_size, void* d_ws, size_t ws_size,
                              hipStream_t stream) {
  const float* X  = (const float*)d_in[0];
  const float* Wq = (const float*)d_in[1];
  const float* bq = (const float*)d_in[2];
  const float* Wk = (const float*)d_in[3];
  const float* bk = (const float*)d_in[4];
  const float* Wv = (const float*)d_in[5];
  const float* bv = (const float*)d_in[6];
  const float* Wo = (const float*)d_in[7];
  const float* bo = (const float*)d_in[8];

  unsigned short* ws = (unsigned short*)d_ws;
  unsigned short* Xbf = ws;                               // 4M elems
  unsigned short* WqT = Xbf + (size_t)MTOK * EMBED;       // 1M each; WqT/WkT/WvT contiguous
  unsigned short* WkT = WqT + (size_t)EMBED * EMBED;
  unsigned short* WvT = WkT + (size_t)EMBED * EMBED;
  unsigned short* WoT = WvT + (size_t)EMBED * EMBED;
  unsigned short* Qb  = WoT + (size_t)EMBED * EMBED;
  unsigned short* Kb  = Qb + (size_t)MTOK * EMBED;
  unsigned short* Vt  = Kb + (size_t)MTOK * EMBED;
  unsigned short* Ctx = Vt + (size_t)MTOK * EMBED;

  cast_bf16_k<<<(MTOK * EMBED / 4 + 255) / 256, 256, 0, stream>>>(X, Xbf,
                                                                  MTOK * EMBED / 4);
  transpose_cast4_k<<<dim3(16, 16, 4), 256, 0, stream>>>(Wq, Wk, Wv, Wo,
                                                         WqT, WkT, WvT, WoT);

  // fused QKV projection: Bt = [WqT;WkT;WvT] (contiguous), N=3072
  gemm_k<0, 128><<<dim3(MTOK / 128, 3072 / 128), 256, 0, stream>>>(
      Xbf, WqT, bq, bk, bv, Qb, Kb, Vt, nullptr);

  attn_k<<<dim3(SEQ / 64, BATCH * NHEAD), 256, 0, stream>>>(Qb, Kb, Vt, Ctx);

  // output projection, BM=64 for 512 blocks (2/CU)
  gemm_k<1, 64><<<dim3(MTOK / 64, EMBED / 128), 256, 0, stream>>>(
      Ctx, WoT, bo, nullptr, nullptr, nullptr, nullptr, nullptr, (float*)d_out);
}